// Round 6
// baseline (4830.255 us; speedup 1.0000x reference)
//
#include <hip/hip_runtime.h>
#include <cstdint>
#include <cstddef>

typedef __attribute__((ext_vector_type(8))) short short8;
typedef __attribute__((ext_vector_type(4))) float f32x4;
typedef __attribute__((ext_vector_type(4))) unsigned short us4;

#define N_SPK 64
#define M_UTT 10
#define T_SEQ 160
#define IN_F  40
#define H_DIM 256
#define B_TOT 640
#define G4    1024

__device__ __forceinline__ unsigned short f2bf(float f) {
  unsigned int u = __float_as_uint(f);
  u += 0x7FFFu + ((u >> 16) & 1u);   // round-to-nearest-even
  return (unsigned short)(u >> 16);
}
__device__ __forceinline__ float b2f(unsigned short u) {
  return __uint_as_float(((unsigned int)u) << 16);
}
__device__ __forceinline__ float sigm(float x) {
  return 1.f / (1.f + __expf(-x));
}
__device__ __forceinline__ float tanh_fast(float x) {
  return 1.f - 2.f / (1.f + __expf(2.f * x));
}

// ---------------------------------------------------------------------------
// Weight pack: B-fragment order for mfma_f32_16x16x32_bf16 (verified R1/R3/R4).
// ---------------------------------------------------------------------------
__global__ void pack_w_kernel(const float* __restrict__ W, short* __restrict__ out,
                              int Kin, int Ktiles) {
  int idx = blockIdx.x * 256 + threadIdx.x;
  int total = 64 * Ktiles * 64;
  if (idx >= total) return;
  int lane = idx & 63;
  int rest = idx >> 6;
  int ks   = rest % Ktiles;
  int tile = rest / Ktiles;
  int n  = tile * 16 + (lane & 15);
  int k0 = ks * 32 + (lane >> 4) * 8;
  short8 v;
#pragma unroll
  for (int j = 0; j < 8; ++j) {
    int k = k0 + j;
    float f = (k < Kin) ? W[(size_t)n * Kin + k] : 0.f;
    v[j] = (short)f2bf(f);
  }
  *(short8*)&out[(size_t)idx * 8] = v;
}

__global__ void bias_sum_kernel(const float* __restrict__ a, const float* __restrict__ b,
                                float* __restrict__ o) {
  int i = blockIdx.x * 256 + threadIdx.x;
  if (i < G4) o[i] = a[i] + b[i];
}

// ---------------------------------------------------------------------------
// Phase A: G = X@Wih^T + bias (bf16, C-layout). 4 tiles/wave (acc = 64 regs),
// grid = 40 btiles x (steps/16) chunks x 4 tile-groups. (R5 retile, re-audited)
// ---------------------------------------------------------------------------
template<int KT, int L0>
__global__ __launch_bounds__(256, 2)
void gate_gemm(const float* __restrict__ seq, const unsigned short* __restrict__ Xf,
               const short* __restrict__ Wp, const float* __restrict__ bias,
               unsigned short* __restrict__ G, int chunk_t0) {
  const int btile = blockIdx.x % 40;
  const int rest  = blockIdx.x / 40;
  const int tg    = rest & 3;
  const int chunk = rest >> 2;
  const int tid = threadIdx.x, lane = tid & 63, wave = tid >> 6;
  const int nl = lane & 15, mq = lane >> 4;

  for (int mg = 0; mg < 4; ++mg) {
    const int slot0 = chunk * 16 + mg * 4;
    const int t0 = chunk_t0 + slot0;
    f32x4 acc[4][4];
#pragma unroll
    for (int q = 0; q < 4; ++q) {
      int tile = tg * 16 + wave + 4 * q;
      float bv = bias[tile * 16 + nl];
#pragma unroll
      for (int mm = 0; mm < 4; ++mm) acc[mm][q] = (f32x4){bv, bv, bv, bv};
    }
    for (int kt = 0; kt < KT; ++kt) {
      short8 a[4];
      if (L0) {
        const int m = btile * 16 + nl;
        const int k0 = kt * 32 + mq * 8;
#pragma unroll
        for (int mm = 0; mm < 4; ++mm) {
#pragma unroll
          for (int j = 0; j < 8; ++j) {
            int k = k0 + j;
            float f = (k < IN_F) ? seq[((size_t)m * T_SEQ + (t0 + mm)) * IN_F + k] : 0.f;
            a[mm][j] = (short)f2bf(f);
          }
        }
      } else {
#pragma unroll
        for (int mm = 0; mm < 4; ++mm)
          a[mm] = *(const short8*)&Xf[(((size_t)(t0 + mm) * 40 + btile) * KT + kt) * 512 + lane * 8];
      }
#pragma unroll
      for (int q = 0; q < 4; ++q) {
        int tile = tg * 16 + wave + 4 * q;
        short8 b = *(const short8*)&Wp[(((size_t)tile * KT + kt) * 64 + lane) * 8];
#pragma unroll
        for (int mm = 0; mm < 4; ++mm)
          acc[mm][q] = __builtin_amdgcn_mfma_f32_16x16x32_bf16(a[mm], b, acc[mm][q], 0, 0, 0);
      }
    }
#pragma unroll
    for (int mm = 0; mm < 4; ++mm)
#pragma unroll
      for (int q = 0; q < 4; ++q) {
        int tile = tg * 16 + wave + 4 * q;
        us4 o;
#pragma unroll
        for (int r = 0; r < 4; ++r) o[r] = f2bf(acc[mm][q][r]);
        *(us4*)&G[(((size_t)(slot0 + mm) * 40 + btile) * 64 + tile) * 256 + lane * 4] = o;
      }
  }
}

// ---------------------------------------------------------------------------
// Phase B: recurrence, 4-block cluster per btile (R5 AGPR-asm abandoned).
// Block (btile, hb) owns h-cols [hb*64, hb*64+64): 16 tiles; 4 waves; wave w
// owns tiles {g*16 + hb*4 + w}: weights = 4x8 short8 = 128 VGPR. No LDS
// weights, no spill. Per-step h-exchange with 3 peers via agent-scope
// release/acquire flags + L2/LLC slab. 160 blocks, 1/CU (forced by dynamic
// LDS padding) -> all co-resident, no deadlock.
// ---------------------------------------------------------------------------
template<int WRITE_H>
__global__ __launch_bounds__(256, 1)
void lstm_rec(const short* __restrict__ Whh_p, const unsigned short* __restrict__ G,
              const int* __restrict__ lens, unsigned short* __restrict__ hseq,
              unsigned short* __restrict__ hxch, int* __restrict__ flags,
              float* __restrict__ c_state, int t_start, int t_end) {
  const int btile = blockIdx.x % 40;
  const int hb    = blockIdx.x / 40;      // h-group 0..3
  const int tid = threadIdx.x, lane = tid & 63, wave = tid >> 6;  // wave 0..3
  const int mq = lane >> 4, nl = lane & 15;
  const int colown = hb * 64 + wave * 16 + nl;

  __shared__ unsigned short h_sh[16][264];   // all 256 h-cols, 16 samples

  // weights: this wave's 16-tile column-slice, fully in VGPRs (128 regs)
  short8 wreg[4][8];
#pragma unroll
  for (int g = 0; g < 4; ++g) {
    const int tile = g * 16 + hb * 4 + wave;
#pragma unroll
    for (int kt = 0; kt < 8; ++kt)
      wreg[g][kt] = *(const short8*)&Whh_p[(((size_t)tile * 8 + kt) * 64 + lane) * 8];
  }
  // h_{t_start-1}: all 4 slabs -> LDS
  for (int i = tid; i < 512; i += 256) {
    int g4 = i >> 7, j = i & 127;
    *(short8*)&h_sh[j >> 3][g4 * 64 + (j & 7) * 8] =
        *(const short8*)&hxch[((size_t)(btile * 4 + g4)) * 1024 + (size_t)j * 8];
  }
  float c_reg[4];
#pragma unroll
  for (int r = 0; r < 4; ++r)
    c_reg[r] = c_state[(size_t)btile * 4096 + (size_t)(mq * 4 + r) * 256 + colown];
  int lenr[4];
#pragma unroll
  for (int r = 0; r < 4; ++r) lenr[r] = lens[btile * 16 + mq * 4 + r];
  __syncthreads();

  // G prefetch for first step
  us4 gcur[4], gnext[4];
  {
    const unsigned short* gb = G + ((size_t)0 * 40 + btile) * 16384 + lane * 4;
#pragma unroll
    for (int g = 0; g < 4; ++g)
      gcur[g] = *(const us4*)&gb[(size_t)(g * 16 + hb * 4 + wave) * 256];
  }

  for (int t = t_start; t < t_end; ++t) {
    // acc init = gate pre-activations; then += h_prev @ Whh^T
    f32x4 acc[4];
#pragma unroll
    for (int g = 0; g < 4; ++g)
#pragma unroll
      for (int r = 0; r < 4; ++r) acc[g][r] = b2f(gcur[g][r]);
#pragma unroll
    for (int kt = 0; kt < 8; ++kt) {
      short8 a = *(const short8*)&h_sh[nl][kt * 32 + mq * 8];
#pragma unroll
      for (int g = 0; g < 4; ++g)
        acc[g] = __builtin_amdgcn_mfma_f32_16x16x32_bf16(a, wreg[g][kt], acc[g], 0, 0, 0);
    }
    // gates (C/D: row = mq*4+r = sample, col = nl)
    unsigned short hv[4];
#pragma unroll
    for (int r = 0; r < 4; ++r) {
      float cn = sigm(acc[1][r]) * c_reg[r] + sigm(acc[0][r]) * tanh_fast(acc[2][r]);
      float hn = sigm(acc[3][r]) * tanh_fast(cn);
      bool upd = (t < lenr[r]);
      if (upd) c_reg[r] = cn;
      hv[r] = upd ? f2bf(hn) : h_sh[mq * 4 + r][colown];  // frozen value
    }
    __syncthreads();                      // (1) everyone done reading h_sh
#pragma unroll
    for (int r = 0; r < 4; ++r) h_sh[mq * 4 + r][colown] = hv[r];
    __syncthreads();                      // (2) own region updated
    // own slab -> global (coalesced short8 from LDS)
    if (tid < 128) {
      int m = tid >> 3, k8 = tid & 7;
      short8 v = *(const short8*)&h_sh[m][hb * 64 + k8 * 8];
      *(short8*)&hxch[((size_t)(btile * 4 + hb)) * 1024 + (size_t)tid * 8] = v;
    }
    if (WRITE_H && tid < 128) {           // h_t in A-frag layout for next layer
      int w2 = tid >> 6, kt = 2 * hb + w2, ln = tid & 63;
      short8 v = *(const short8*)&h_sh[ln & 15][kt * 32 + (ln >> 4) * 8];
      *(short8*)&hseq[(((size_t)t * 40 + btile) * 8 + kt) * 512 + (size_t)ln * 8] = v;
    }
    __syncthreads();                      // (3) slab stores issued+drained (vmcnt0 at barrier)
    if (tid == 0) {
      __builtin_amdgcn_fence(__ATOMIC_RELEASE, "agent");
      __hip_atomic_store(&flags[btile * 4 + hb], t + 1, __ATOMIC_RELAXED,
                         __HIP_MEMORY_SCOPE_AGENT);
    }
    // prefetch next step's G while peers finish (hides HBM latency)
    {
      int tt = (t + 1 < t_end) ? (t + 1) : t;
      const unsigned short* gb = G + ((size_t)(tt - t_start) * 40 + btile) * 16384 + lane * 4;
#pragma unroll
      for (int g = 0; g < 4; ++g)
        gnext[g] = *(const us4*)&gb[(size_t)(g * 16 + hb * 4 + wave) * 256];
    }
    if (tid < 3) {
      int p = tid + (tid >= hb ? 1 : 0);
      while (__hip_atomic_load(&flags[btile * 4 + p], __ATOMIC_RELAXED,
                               __HIP_MEMORY_SCOPE_AGENT) < t + 1) {}
    }
    __syncthreads();                      // (4) peers ready
    __builtin_amdgcn_fence(__ATOMIC_ACQUIRE, "agent");
    // pull 3 peer slabs -> LDS
    for (int i = tid; i < 384; i += 256) {
      int pp = i >> 7, j = i & 127;
      int p = pp + (pp >= hb ? 1 : 0);
      short8 v = *(const short8*)&hxch[((size_t)(btile * 4 + p)) * 1024 + (size_t)j * 8];
      *(short8*)&h_sh[j >> 3][p * 64 + (j & 7) * 8] = v;
    }
    __syncthreads();                      // (5) h_t complete in LDS
#pragma unroll
    for (int g = 0; g < 4; ++g) gcur[g] = gnext[g];
  }

  // persist c (chunk boundary / final E)
#pragma unroll
  for (int r = 0; r < 4; ++r)
    c_state[(size_t)btile * 4096 + (size_t)(mq * 4 + r) * 256 + colown] = c_reg[r];
}

// ---------------------------------------------------------------------------
// Epilogue (verified R1/R3/R4). E aliases c_state.
// ---------------------------------------------------------------------------
__global__ void k_norm(const float* __restrict__ E, float* __restrict__ E1,
                       float* __restrict__ En) {
  int row  = blockIdx.x * 4 + (threadIdx.x >> 6);
  int lane = threadIdx.x & 63;
  const float* e = E + (size_t)row * H_DIM;
  float v[4]; float ss = 0.f;
#pragma unroll
  for (int j = 0; j < 4; ++j) { v[j] = e[lane + 64 * j]; ss += v[j] * v[j]; }
#pragma unroll
  for (int m = 32; m >= 1; m >>= 1) ss += __shfl_xor(ss, m, 64);
  float nrm  = sqrtf(ss);
  float inv1 = 1.f / fmaxf(nrm, 1e-12f);
  float inv2 = 1.f / fmaxf(nrm * inv1, 1e-8f);
#pragma unroll
  for (int j = 0; j < 4; ++j) {
    float e1 = v[j] * inv1;
    E1[(size_t)row * H_DIM + lane + 64 * j] = e1;
    En[(size_t)row * H_DIM + lane + 64 * j] = e1 * inv2;
  }
}

__global__ void k_cent(const float* __restrict__ E1, float* __restrict__ C,
                       float* __restrict__ CnT) {
  int n = blockIdx.x;
  int lane = threadIdx.x;  // 64
  float v[4]; float ss = 0.f;
#pragma unroll
  for (int j = 0; j < 4; ++j) {
    int col = lane + 64 * j;
    float s = 0.f;
    for (int m = 0; m < M_UTT; ++m) s += E1[((size_t)n * M_UTT + m) * H_DIM + col];
    v[j] = s / (float)M_UTT;
    ss += v[j] * v[j];
  }
#pragma unroll
  for (int m = 32; m >= 1; m >>= 1) ss += __shfl_xor(ss, m, 64);
  float inv = 1.f / fmaxf(sqrtf(ss), 1e-8f);
#pragma unroll
  for (int j = 0; j < 4; ++j) {
    int col = lane + 64 * j;
    C[(size_t)n * H_DIM + col]  = v[j];
    CnT[(size_t)col * N_SPK + n] = v[j] * inv;
  }
}

__global__ void k_cm(const float* __restrict__ E1, const float* __restrict__ C,
                     float* __restrict__ Cmn) {
  int b    = blockIdx.x * 4 + (threadIdx.x >> 6);
  int lane = threadIdx.x & 63;
  int spk  = b / M_UTT;
  float v[4]; float ss = 0.f;
#pragma unroll
  for (int j = 0; j < 4; ++j) {
    int col = lane + 64 * j;
    v[j] = ((float)M_UTT * C[(size_t)spk * H_DIM + col] + E1[(size_t)b * H_DIM + col])
           / (float)(M_UTT - 1);
    ss += v[j] * v[j];
  }
#pragma unroll
  for (int m = 32; m >= 1; m >>= 1) ss += __shfl_xor(ss, m, 64);
  float inv = 1.f / fmaxf(sqrtf(ss), 1e-8f);
#pragma unroll
  for (int j = 0; j < 4; ++j)
    Cmn[(size_t)b * H_DIM + lane + 64 * j] = v[j] * inv;
}

__global__ void k_sim(const float* __restrict__ En, const float* __restrict__ CnT,
                      const float* __restrict__ Cmn, const float* __restrict__ w_sim,
                      const float* __restrict__ b_sim, float* __restrict__ S) {
  int b = blockIdx.x;
  int n = threadIdx.x;  // 64
  int diag = b / M_UTT;
  float w = w_sim[0], bb = b_sim[0];
  float s = 0.f;
  for (int k = 0; k < H_DIM; ++k) {
    float en = En[(size_t)b * H_DIM + k];
    float c  = (n == diag) ? Cmn[(size_t)b * H_DIM + k] : CnT[(size_t)k * N_SPK + n];
    s += en * c;
  }
  S[(size_t)b * N_SPK + n] = s * w + bb;
}

// ---------------------------------------------------------------------------
// Workspace layout (bytes). Fixed part then runtime-sized G chunk.
// ---------------------------------------------------------------------------
#define O_WHH   0ull            // 1572864
#define O_WIH0  1572864ull      // 131072
#define O_WIH1  1703936ull      // 524288
#define O_WIH2  2228224ull      // 524288
#define O_BIAS  2752512ull      // 12288
#define O_CST   2764800ull      // 655360 (fp32 c; aliases E)
#define O_XCH   3420160ull      // 327680 (h exchange slabs)
#define O_FLG   3747840ull      // 4096
#define O_HSEQ  3751936ull      // 52428800
#define O_G     56180736ull     // TC * 1310720

extern "C" void kernel_launch(void* const* d_in, const int* in_sizes, int n_in,
                              void* d_out, int out_size, void* d_ws, size_t ws_size,
                              hipStream_t stream) {
  const float* seq   = (const float*)d_in[0];
  const int*   lens  = (const int*)d_in[1];
  const float* w_sim = (const float*)d_in[2];
  const float* b_sim = (const float*)d_in[3];
  const float* Wih[3] = {(const float*)d_in[4],  (const float*)d_in[8],  (const float*)d_in[12]};
  const float* Whh[3] = {(const float*)d_in[5],  (const float*)d_in[9],  (const float*)d_in[13]};
  const float* bih[3] = {(const float*)d_in[6],  (const float*)d_in[10], (const float*)d_in[14]};
  const float* bhh[3] = {(const float*)d_in[7],  (const float*)d_in[11], (const float*)d_in[15]};

  char* ws = (char*)d_ws;
  short* Whhp[3] = {(short*)(ws + O_WHH), (short*)(ws + O_WHH + 524288),
                    (short*)(ws + O_WHH + 1048576)};
  short* Wihp[3] = {(short*)(ws + O_WIH0), (short*)(ws + O_WIH1), (short*)(ws + O_WIH2)};
  float* biasc = (float*)(ws + O_BIAS);
  float* c_state = (float*)(ws + O_CST);
  unsigned short* hxch = (unsigned short*)(ws + O_XCH);
  int* flags = (int*)(ws + O_FLG);
  unsigned short* hseq = (unsigned short*)(ws + O_HSEQ);
  unsigned short* G    = (unsigned short*)(ws + O_G);
  float* E1  = (float*)(ws + O_G);
  float* En  = (float*)(ws + O_G + 655360);
  float* C   = (float*)(ws + O_G + 1310720);
  float* CnT = (float*)(ws + O_G + 1376256);
  float* Cmn = (float*)(ws + O_G + 1441792);
  float* S   = (float*)d_out;

  const size_t base = O_G, per16 = 16ull * 40 * 64 * 256 * 2;
  int units = (ws_size > base) ? (int)((ws_size - base) / per16) : 0;
  int TC = units * 16;
  if (TC > T_SEQ) TC = T_SEQ;
  if (TC < 16) TC = 16;

  pack_w_kernel<<<32, 256, 0, stream>>>(Wih[0], Wihp[0], IN_F, 2);
  pack_w_kernel<<<128, 256, 0, stream>>>(Whh[0], Whhp[0], H_DIM, 8);
  pack_w_kernel<<<128, 256, 0, stream>>>(Wih[1], Wihp[1], H_DIM, 8);
  pack_w_kernel<<<128, 256, 0, stream>>>(Whh[1], Whhp[1], H_DIM, 8);
  pack_w_kernel<<<128, 256, 0, stream>>>(Wih[2], Wihp[2], H_DIM, 8);
  pack_w_kernel<<<128, 256, 0, stream>>>(Whh[2], Whhp[2], H_DIM, 8);
  for (int l = 0; l < 3; ++l)
    bias_sum_kernel<<<4, 256, 0, stream>>>(bih[l], bhh[l], biasc + l * G4);

  for (int l = 0; l < 3; ++l) {
    hipMemsetAsync(c_state, 0, 655360, stream);
    hipMemsetAsync(hxch, 0, 327680, stream);
    hipMemsetAsync(flags, 0, 4096, stream);
    for (int t0 = 0; t0 < T_SEQ; t0 += TC) {
      int steps = T_SEQ - t0; if (steps > TC) steps = TC;
      int ggrid = 40 * (steps / 16) * 4;
      if (l == 0)
        gate_gemm<2, 1><<<ggrid, 256, 0, stream>>>(seq, nullptr, Wihp[0], biasc, G, t0);
      else
        gate_gemm<8, 0><<<ggrid, 256, 0, stream>>>(nullptr, hseq, Wihp[l], biasc + l * G4, G, t0);
      // dynamic LDS padding (120000 B) forces 1 block/CU -> 160 co-resident blocks
      if (l < 2)
        lstm_rec<1><<<160, 256, 120000, stream>>>(Whhp[l], G, lens, hseq, hxch, flags,
                                                  c_state, t0, t0 + steps);
      else
        lstm_rec<0><<<160, 256, 120000, stream>>>(Whhp[l], G, lens, nullptr, hxch, flags,
                                                  c_state, t0, t0 + steps);
    }
  }

  k_norm<<<160, 256, 0, stream>>>(c_state, E1, En);
  k_cent<<<N_SPK, 64, 0, stream>>>(E1, C, CnT);
  k_cm<<<160, 256, 0, stream>>>(E1, C, Cmn);
  k_sim<<<B_TOT, 64, 0, stream>>>(En, CnT, Cmn, w_sim, b_sim, S);
}

// Round 7
// 2025.651 us; speedup vs baseline: 2.3845x; 2.3845x over previous
//
#include <hip/hip_runtime.h>
#include <cstdint>
#include <cstddef>

typedef __attribute__((ext_vector_type(8))) short short8;
typedef __attribute__((ext_vector_type(4))) float f32x4;
typedef __attribute__((ext_vector_type(4))) unsigned short us4;

#define N_SPK 64
#define M_UTT 10
#define T_SEQ 160
#define IN_F  40
#define H_DIM 256
#define B_TOT 640
#define G4    1024

__device__ __forceinline__ unsigned short f2bf(float f) {
  unsigned int u = __float_as_uint(f);
  u += 0x7FFFu + ((u >> 16) & 1u);   // round-to-nearest-even
  return (unsigned short)(u >> 16);
}
__device__ __forceinline__ float b2f(unsigned short u) {
  return __uint_as_float(((unsigned int)u) << 16);
}
__device__ __forceinline__ float sigm(float x) {
  return 1.f / (1.f + __expf(-x));
}
__device__ __forceinline__ float tanh_fast(float x) {
  return 1.f - 2.f / (1.f + __expf(2.f * x));
}

// ---------------------------------------------------------------------------
// Weight pack: B-fragment order for mfma_f32_16x16x32_bf16 (verified R1/R3/R4).
// ---------------------------------------------------------------------------
__global__ void pack_w_kernel(const float* __restrict__ W, short* __restrict__ out,
                              int Kin, int Ktiles) {
  int idx = blockIdx.x * 256 + threadIdx.x;
  int total = 64 * Ktiles * 64;
  if (idx >= total) return;
  int lane = idx & 63;
  int rest = idx >> 6;
  int ks   = rest % Ktiles;
  int tile = rest / Ktiles;
  int n  = tile * 16 + (lane & 15);
  int k0 = ks * 32 + (lane >> 4) * 8;
  short8 v;
#pragma unroll
  for (int j = 0; j < 8; ++j) {
    int k = k0 + j;
    float f = (k < Kin) ? W[(size_t)n * Kin + k] : 0.f;
    v[j] = (short)f2bf(f);
  }
  *(short8*)&out[(size_t)idx * 8] = v;
}

__global__ void bias_sum_kernel(const float* __restrict__ a, const float* __restrict__ b,
                                float* __restrict__ o) {
  int i = blockIdx.x * 256 + threadIdx.x;
  if (i < G4) o[i] = a[i] + b[i];
}

// ---------------------------------------------------------------------------
// Phase A: G = X@Wih^T + bias (bf16, C-layout). 4 tiles/wave, verified R6.
// ---------------------------------------------------------------------------
template<int KT, int L0>
__global__ __launch_bounds__(256, 2)
void gate_gemm(const float* __restrict__ seq, const unsigned short* __restrict__ Xf,
               const short* __restrict__ Wp, const float* __restrict__ bias,
               unsigned short* __restrict__ G, int chunk_t0) {
  const int btile = blockIdx.x % 40;
  const int rest  = blockIdx.x / 40;
  const int tg    = rest & 3;
  const int chunk = rest >> 2;
  const int tid = threadIdx.x, lane = tid & 63, wave = tid >> 6;
  const int nl = lane & 15, mq = lane >> 4;

  for (int mg = 0; mg < 4; ++mg) {
    const int slot0 = chunk * 16 + mg * 4;
    const int t0 = chunk_t0 + slot0;
    f32x4 acc[4][4];
#pragma unroll
    for (int q = 0; q < 4; ++q) {
      int tile = tg * 16 + wave + 4 * q;
      float bv = bias[tile * 16 + nl];
#pragma unroll
      for (int mm = 0; mm < 4; ++mm) acc[mm][q] = (f32x4){bv, bv, bv, bv};
    }
    for (int kt = 0; kt < KT; ++kt) {
      short8 a[4];
      if (L0) {
        const int m = btile * 16 + nl;
        const int k0 = kt * 32 + mq * 8;
#pragma unroll
        for (int mm = 0; mm < 4; ++mm) {
#pragma unroll
          for (int j = 0; j < 8; ++j) {
            int k = k0 + j;
            float f = (k < IN_F) ? seq[((size_t)m * T_SEQ + (t0 + mm)) * IN_F + k] : 0.f;
            a[mm][j] = (short)f2bf(f);
          }
        }
      } else {
#pragma unroll
        for (int mm = 0; mm < 4; ++mm)
          a[mm] = *(const short8*)&Xf[(((size_t)(t0 + mm) * 40 + btile) * KT + kt) * 512 + lane * 8];
      }
#pragma unroll
      for (int q = 0; q < 4; ++q) {
        int tile = tg * 16 + wave + 4 * q;
        short8 b = *(const short8*)&Wp[(((size_t)tile * KT + kt) * 64 + lane) * 8];
#pragma unroll
        for (int mm = 0; mm < 4; ++mm)
          acc[mm][q] = __builtin_amdgcn_mfma_f32_16x16x32_bf16(a[mm], b, acc[mm][q], 0, 0, 0);
      }
    }
#pragma unroll
    for (int mm = 0; mm < 4; ++mm)
#pragma unroll
      for (int q = 0; q < 4; ++q) {
        int tile = tg * 16 + wave + 4 * q;
        us4 o;
#pragma unroll
        for (int r = 0; r < 4; ++r) o[r] = f2bf(acc[mm][q][r]);
        *(us4*)&G[(((size_t)(slot0 + mm) * 40 + btile) * 64 + tile) * 256 + lane * 4] = o;
      }
  }
}

// ---------------------------------------------------------------------------
// Phase B: 4-block cluster per btile; exchange via agent-scope RELAXED atomics
// (sc1 -> LLC direct; NO cache-wide fences, the R6 killer). Parity-double-
// buffered slabs remove the t/t+1 overwrite race. 160 blocks <= 256 CUs ->
// co-resident; 100 KB static LDS pad forces 1 block/CU spreading.
// Per block: 16 tiles of Whh in 128 regs/wave (AGPR-backed, verified R6).
// ---------------------------------------------------------------------------
template<int WRITE_H>
__global__ __launch_bounds__(256, 1)
void lstm_rec(const short* __restrict__ Whh_p, const unsigned short* __restrict__ G,
              const int* __restrict__ lens, unsigned short* __restrict__ hseq,
              unsigned int* __restrict__ hxch, int* __restrict__ flags,
              float* __restrict__ c_state, int t_start, int t_end) {
  const int btile = blockIdx.x % 40;
  const int hb    = blockIdx.x / 40;      // h-group 0..3
  const int tid = threadIdx.x, lane = tid & 63, wave = tid >> 6;  // wave 0..3
  const int mq = lane >> 4, nl = lane & 15;
  const int colown = hb * 64 + wave * 16 + nl;

  __shared__ unsigned short h_sh[16][264];   // all 256 h-cols, 16 samples
  __shared__ char pad_[100000];              // occupancy shaping: 1 block/CU
  if (tid == 0) pad_[0] = (char)t_start;

  // weights: this wave's 16-tile column-slice in regs (128, AGPR-backed)
  short8 wreg[4][8];
#pragma unroll
  for (int g = 0; g < 4; ++g) {
    const int tile = g * 16 + hb * 4 + wave;
#pragma unroll
    for (int kt = 0; kt < 8; ++kt)
      wreg[g][kt] = *(const short8*)&Whh_p[(((size_t)tile * 8 + kt) * 64 + lane) * 8];
  }
  // h_{t_start-1}: all 4 slabs (parity of t_start-1) -> LDS
  {
    int par0 = (t_start - 1) & 1;
    for (int i = tid; i < 2048; i += 256) {
      int g4 = i >> 9, j = i & 511;
      unsigned int u = __hip_atomic_load(
          &hxch[((size_t)(par0 * 160 + btile * 4 + g4)) * 512 + j],
          __ATOMIC_RELAXED, __HIP_MEMORY_SCOPE_AGENT);
      *(unsigned int*)&h_sh[j >> 5][g4 * 64 + (j & 31) * 2] = u;
    }
  }
  float c_reg[4];
#pragma unroll
  for (int r = 0; r < 4; ++r)
    c_reg[r] = c_state[(size_t)btile * 4096 + (size_t)(mq * 4 + r) * 256 + colown];
  int lenr[4];
#pragma unroll
  for (int r = 0; r < 4; ++r) lenr[r] = lens[btile * 16 + mq * 4 + r];
  __syncthreads();

  // G prefetch for first step
  us4 gcur[4], gnext[4];
  {
    const unsigned short* gb = G + ((size_t)0 * 40 + btile) * 16384 + lane * 4;
#pragma unroll
    for (int g = 0; g < 4; ++g)
      gcur[g] = *(const us4*)&gb[(size_t)(g * 16 + hb * 4 + wave) * 256];
  }

  for (int t = t_start; t < t_end; ++t) {
    const int par = t & 1;
    // acc init = gate pre-activations; then += h_prev @ Whh^T
    f32x4 acc[4];
#pragma unroll
    for (int g = 0; g < 4; ++g)
#pragma unroll
      for (int r = 0; r < 4; ++r) acc[g][r] = b2f(gcur[g][r]);
#pragma unroll
    for (int kt = 0; kt < 8; ++kt) {
      short8 a = *(const short8*)&h_sh[nl][kt * 32 + mq * 8];
#pragma unroll
      for (int g = 0; g < 4; ++g)
        acc[g] = __builtin_amdgcn_mfma_f32_16x16x32_bf16(a, wreg[g][kt], acc[g], 0, 0, 0);
    }
    // gates (C/D: row = mq*4+r = sample, col = nl)
    unsigned short hv[4];
#pragma unroll
    for (int r = 0; r < 4; ++r) {
      float cn = sigm(acc[1][r]) * c_reg[r] + sigm(acc[0][r]) * tanh_fast(acc[2][r]);
      float hn = sigm(acc[3][r]) * tanh_fast(cn);
      bool upd = (t < lenr[r]);
      if (upd) c_reg[r] = cn;
      hv[r] = upd ? f2bf(hn) : h_sh[mq * 4 + r][colown];  // frozen value
    }
    __syncthreads();                      // (1) all reads of h_{t-1} done
#pragma unroll
    for (int r = 0; r < 4; ++r) h_sh[mq * 4 + r][colown] = hv[r];
    __syncthreads();                      // (2) own 64 cols updated in LDS
    // own slab -> LLC (relaxed agent atomics = sc1, no fence)
    {
      const size_t base = (size_t)(par * 160 + btile * 4 + hb) * 512;
      for (int i = tid; i < 512; i += 256) {
        unsigned int u = *(const unsigned int*)&h_sh[i >> 5][hb * 64 + (i & 31) * 2];
        __hip_atomic_store(&hxch[base + i], u, __ATOMIC_RELAXED,
                           __HIP_MEMORY_SCOPE_AGENT);
      }
    }
    if (WRITE_H && tid < 128) {           // h_t in A-frag layout for next layer
      int w2 = tid >> 6, kt = 2 * hb + w2, ln = tid & 63;
      short8 v = *(const short8*)&h_sh[ln & 15][kt * 32 + (ln >> 4) * 8];
      *(short8*)&hseq[(((size_t)t * 40 + btile) * 8 + kt) * 512 + (size_t)ln * 8] = v;
    }
    __syncthreads();                      // (3) every thread drained vmcnt(0)
    if (tid == 0)
      __hip_atomic_store(&flags[btile * 4 + hb], t + 1, __ATOMIC_RELAXED,
                         __HIP_MEMORY_SCOPE_AGENT);
    // prefetch next step's G while peers finish
    {
      int tt = (t + 1 < t_end) ? (t + 1) : t;
      const unsigned short* gb = G + ((size_t)(tt - t_start) * 40 + btile) * 16384 + lane * 4;
#pragma unroll
      for (int g = 0; g < 4; ++g)
        gnext[g] = *(const us4*)&gb[(size_t)(g * 16 + hb * 4 + wave) * 256];
    }
    if (tid < 3) {
      int p = tid + (tid >= hb ? 1 : 0);
      while (__hip_atomic_load(&flags[btile * 4 + p], __ATOMIC_RELAXED,
                               __HIP_MEMORY_SCOPE_AGENT) < t + 1) {}
    }
    __syncthreads();                      // (4) peers' slabs at LLC
    // pull 3 peer slabs -> LDS (sc1 loads read LLC regardless of L2 state)
    {
      const size_t pbase = (size_t)(par * 160 + btile * 4) * 512;
      for (int i = tid; i < 1536; i += 256) {
        int pp = i >> 9, j = i & 511;
        int p = pp + (pp >= hb ? 1 : 0);
        unsigned int u = __hip_atomic_load(&hxch[pbase + (size_t)p * 512 + j],
                                           __ATOMIC_RELAXED, __HIP_MEMORY_SCOPE_AGENT);
        *(unsigned int*)&h_sh[j >> 5][p * 64 + (j & 31) * 2] = u;
      }
    }
    __syncthreads();                      // (5) h_t complete in LDS
#pragma unroll
    for (int g = 0; g < 4; ++g) gcur[g] = gnext[g];
  }

  // persist c (chunk boundary / final E)
#pragma unroll
  for (int r = 0; r < 4; ++r)
    c_state[(size_t)btile * 4096 + (size_t)(mq * 4 + r) * 256 + colown] = c_reg[r];
}

// ---------------------------------------------------------------------------
// Epilogue (verified R1/R3/R4). E aliases c_state.
// ---------------------------------------------------------------------------
__global__ void k_norm(const float* __restrict__ E, float* __restrict__ E1,
                       float* __restrict__ En) {
  int row  = blockIdx.x * 4 + (threadIdx.x >> 6);
  int lane = threadIdx.x & 63;
  const float* e = E + (size_t)row * H_DIM;
  float v[4]; float ss = 0.f;
#pragma unroll
  for (int j = 0; j < 4; ++j) { v[j] = e[lane + 64 * j]; ss += v[j] * v[j]; }
#pragma unroll
  for (int m = 32; m >= 1; m >>= 1) ss += __shfl_xor(ss, m, 64);
  float nrm  = sqrtf(ss);
  float inv1 = 1.f / fmaxf(nrm, 1e-12f);
  float inv2 = 1.f / fmaxf(nrm * inv1, 1e-8f);
#pragma unroll
  for (int j = 0; j < 4; ++j) {
    float e1 = v[j] * inv1;
    E1[(size_t)row * H_DIM + lane + 64 * j] = e1;
    En[(size_t)row * H_DIM + lane + 64 * j] = e1 * inv2;
  }
}

__global__ void k_cent(const float* __restrict__ E1, float* __restrict__ C,
                       float* __restrict__ CnT) {
  int n = blockIdx.x;
  int lane = threadIdx.x;  // 64
  float v[4]; float ss = 0.f;
#pragma unroll
  for (int j = 0; j < 4; ++j) {
    int col = lane + 64 * j;
    float s = 0.f;
    for (int m = 0; m < M_UTT; ++m) s += E1[((size_t)n * M_UTT + m) * H_DIM + col];
    v[j] = s / (float)M_UTT;
    ss += v[j] * v[j];
  }
#pragma unroll
  for (int m = 32; m >= 1; m >>= 1) ss += __shfl_xor(ss, m, 64);
  float inv = 1.f / fmaxf(sqrtf(ss), 1e-8f);
#pragma unroll
  for (int j = 0; j < 4; ++j) {
    int col = lane + 64 * j;
    C[(size_t)n * H_DIM + col]  = v[j];
    CnT[(size_t)col * N_SPK + n] = v[j] * inv;
  }
}

__global__ void k_cm(const float* __restrict__ E1, const float* __restrict__ C,
                     float* __restrict__ Cmn) {
  int b    = blockIdx.x * 4 + (threadIdx.x >> 6);
  int lane = threadIdx.x & 63;
  int spk  = b / M_UTT;
  float v[4]; float ss = 0.f;
#pragma unroll
  for (int j = 0; j < 4; ++j) {
    int col = lane + 64 * j;
    v[j] = ((float)M_UTT * C[(size_t)spk * H_DIM + col] + E1[(size_t)b * H_DIM + col])
           / (float)(M_UTT - 1);
    ss += v[j] * v[j];
  }
#pragma unroll
  for (int m = 32; m >= 1; m >>= 1) ss += __shfl_xor(ss, m, 64);
  float inv = 1.f / fmaxf(sqrtf(ss), 1e-8f);
#pragma unroll
  for (int j = 0; j < 4; ++j)
    Cmn[(size_t)b * H_DIM + lane + 64 * j] = v[j] * inv;
}

__global__ void k_sim(const float* __restrict__ En, const float* __restrict__ CnT,
                      const float* __restrict__ Cmn, const float* __restrict__ w_sim,
                      const float* __restrict__ b_sim, float* __restrict__ S) {
  int b = blockIdx.x;
  int n = threadIdx.x;  // 64
  int diag = b / M_UTT;
  float w = w_sim[0], bb = b_sim[0];
  float s = 0.f;
  for (int k = 0; k < H_DIM; ++k) {
    float en = En[(size_t)b * H_DIM + k];
    float c  = (n == diag) ? Cmn[(size_t)b * H_DIM + k] : CnT[(size_t)k * N_SPK + n];
    s += en * c;
  }
  S[(size_t)b * N_SPK + n] = s * w + bb;
}

// ---------------------------------------------------------------------------
// Workspace layout (bytes). Fixed part then runtime-sized G chunk.
// ---------------------------------------------------------------------------
#define O_WHH   0ull            // 1572864
#define O_WIH0  1572864ull      // 131072
#define O_WIH1  1703936ull      // 524288
#define O_WIH2  2228224ull      // 524288
#define O_BIAS  2752512ull      // 12288
#define O_CST   2764800ull      // 655360 (fp32 c; aliases E)
#define O_XCH   3420160ull      // 655360 (2-parity h-exchange slabs, dwords)
#define O_FLG   4075520ull      // 4096
#define O_HSEQ  4079616ull      // 52428800
#define O_G     56508416ull     // TC * 1310720

extern "C" void kernel_launch(void* const* d_in, const int* in_sizes, int n_in,
                              void* d_out, int out_size, void* d_ws, size_t ws_size,
                              hipStream_t stream) {
  const float* seq   = (const float*)d_in[0];
  const int*   lens  = (const int*)d_in[1];
  const float* w_sim = (const float*)d_in[2];
  const float* b_sim = (const float*)d_in[3];
  const float* Wih[3] = {(const float*)d_in[4],  (const float*)d_in[8],  (const float*)d_in[12]};
  const float* Whh[3] = {(const float*)d_in[5],  (const float*)d_in[9],  (const float*)d_in[13]};
  const float* bih[3] = {(const float*)d_in[6],  (const float*)d_in[10], (const float*)d_in[14]};
  const float* bhh[3] = {(const float*)d_in[7],  (const float*)d_in[11], (const float*)d_in[15]};

  char* ws = (char*)d_ws;
  short* Whhp[3] = {(short*)(ws + O_WHH), (short*)(ws + O_WHH + 524288),
                    (short*)(ws + O_WHH + 1048576)};
  short* Wihp[3] = {(short*)(ws + O_WIH0), (short*)(ws + O_WIH1), (short*)(ws + O_WIH2)};
  float* biasc = (float*)(ws + O_BIAS);
  float* c_state = (float*)(ws + O_CST);
  unsigned int* hxch = (unsigned int*)(ws + O_XCH);
  int* flags = (int*)(ws + O_FLG);
  unsigned short* hseq = (unsigned short*)(ws + O_HSEQ);
  unsigned short* G    = (unsigned short*)(ws + O_G);
  float* E1  = (float*)(ws + O_G);
  float* En  = (float*)(ws + O_G + 655360);
  float* C   = (float*)(ws + O_G + 1310720);
  float* CnT = (float*)(ws + O_G + 1376256);
  float* Cmn = (float*)(ws + O_G + 1441792);
  float* S   = (float*)d_out;

  const size_t base = O_G, per16 = 16ull * 40 * 64 * 256 * 2;
  int units = (ws_size > base) ? (int)((ws_size - base) / per16) : 0;
  int TC = units * 16;
  if (TC > T_SEQ) TC = T_SEQ;
  if (TC < 16) TC = 16;

  pack_w_kernel<<<32, 256, 0, stream>>>(Wih[0], Wihp[0], IN_F, 2);
  pack_w_kernel<<<128, 256, 0, stream>>>(Whh[0], Whhp[0], H_DIM, 8);
  pack_w_kernel<<<128, 256, 0, stream>>>(Wih[1], Wihp[1], H_DIM, 8);
  pack_w_kernel<<<128, 256, 0, stream>>>(Whh[1], Whhp[1], H_DIM, 8);
  pack_w_kernel<<<128, 256, 0, stream>>>(Wih[2], Wihp[2], H_DIM, 8);
  pack_w_kernel<<<128, 256, 0, stream>>>(Whh[2], Whhp[2], H_DIM, 8);
  for (int l = 0; l < 3; ++l)
    bias_sum_kernel<<<4, 256, 0, stream>>>(bih[l], bhh[l], biasc + l * G4);

  for (int l = 0; l < 3; ++l) {
    hipMemsetAsync(c_state, 0, 655360, stream);
    hipMemsetAsync(hxch, 0, 655360, stream);
    hipMemsetAsync(flags, 0, 4096, stream);
    for (int t0 = 0; t0 < T_SEQ; t0 += TC) {
      int steps = T_SEQ - t0; if (steps > TC) steps = TC;
      int ggrid = 40 * (steps / 16) * 4;
      if (l == 0)
        gate_gemm<2, 1><<<ggrid, 256, 0, stream>>>(seq, nullptr, Wihp[0], biasc, G, t0);
      else
        gate_gemm<8, 0><<<ggrid, 256, 0, stream>>>(nullptr, hseq, Wihp[l], biasc + l * G4, G, t0);
      if (l < 2)
        lstm_rec<1><<<160, 256, 0, stream>>>(Whhp[l], G, lens, hseq, hxch, flags,
                                             c_state, t0, t0 + steps);
      else
        lstm_rec<0><<<160, 256, 0, stream>>>(Whhp[l], G, lens, nullptr, hxch, flags,
                                             c_state, t0, t0 + steps);
    }
  }

  k_norm<<<160, 256, 0, stream>>>(c_state, E1, En);
  k_cent<<<N_SPK, 64, 0, stream>>>(E1, C, CnT);
  k_cm<<<160, 256, 0, stream>>>(E1, C, Cmn);
  k_sim<<<B_TOT, 64, 0, stream>>>(En, CnT, Cmn, w_sim, b_sim, S);
}

// Round 8
// 2018.486 us; speedup vs baseline: 2.3930x; 1.0035x over previous
//
#include <hip/hip_runtime.h>
#include <cstdint>
#include <cstddef>

typedef __attribute__((ext_vector_type(8))) short short8;
typedef __attribute__((ext_vector_type(4))) float f32x4;
typedef __attribute__((ext_vector_type(4))) unsigned short us4;

#define N_SPK 64
#define M_UTT 10
#define T_SEQ 160
#define IN_F  40
#define H_DIM 256
#define B_TOT 640
#define G4    1024

__device__ __forceinline__ unsigned short f2bf(float f) {
  unsigned int u = __float_as_uint(f);
  u += 0x7FFFu + ((u >> 16) & 1u);   // round-to-nearest-even
  return (unsigned short)(u >> 16);
}
__device__ __forceinline__ float b2f(unsigned short u) {
  return __uint_as_float(((unsigned int)u) << 16);
}
__device__ __forceinline__ float sigm(float x) {
  return 1.f / (1.f + __expf(-x));
}
__device__ __forceinline__ float tanh_fast(float x) {
  return 1.f - 2.f / (1.f + __expf(2.f * x));
}
__device__ __forceinline__ unsigned long long ato_ld(const unsigned long long* p) {
  return __hip_atomic_load(p, __ATOMIC_RELAXED, __HIP_MEMORY_SCOPE_AGENT);
}
__device__ __forceinline__ void ato_st(unsigned long long* p, unsigned long long v) {
  __hip_atomic_store(p, v, __ATOMIC_RELAXED, __HIP_MEMORY_SCOPE_AGENT);
}
__device__ __forceinline__ int flg_ld(const int* p) {
  return __hip_atomic_load(p, __ATOMIC_RELAXED, __HIP_MEMORY_SCOPE_AGENT);
}
__device__ __forceinline__ void flg_st(int* p, int v) {
  __hip_atomic_store(p, v, __ATOMIC_RELAXED, __HIP_MEMORY_SCOPE_AGENT);
}

// ---------------------------------------------------------------------------
// Weight pack: B-fragment order for mfma_f32_16x16x32_bf16 (verified R1-R7).
// ---------------------------------------------------------------------------
__global__ void pack_w_kernel(const float* __restrict__ W, short* __restrict__ out,
                              int Kin, int Ktiles) {
  int idx = blockIdx.x * 256 + threadIdx.x;
  int total = 64 * Ktiles * 64;
  if (idx >= total) return;
  int lane = idx & 63;
  int rest = idx >> 6;
  int ks   = rest % Ktiles;
  int tile = rest / Ktiles;
  int n  = tile * 16 + (lane & 15);
  int k0 = ks * 32 + (lane >> 4) * 8;
  short8 v;
#pragma unroll
  for (int j = 0; j < 8; ++j) {
    int k = k0 + j;
    float f = (k < Kin) ? W[(size_t)n * Kin + k] : 0.f;
    v[j] = (short)f2bf(f);
  }
  *(short8*)&out[(size_t)idx * 8] = v;
}

__global__ void bias_sum_kernel(const float* __restrict__ a, const float* __restrict__ b,
                                float* __restrict__ o) {
  int i = blockIdx.x * 256 + threadIdx.x;
  if (i < G4) o[i] = a[i] + b[i];
}

// ---------------------------------------------------------------------------
// Layer-0 gate GEMM (input is fp32 seq; K pad 40->64, KT=2). Verified R6/R7.
// Grid = 40 btiles x 10 chunks x 4 tile-groups = 1600 blocks.
// ---------------------------------------------------------------------------
__global__ __launch_bounds__(256, 2)
void gate_gemm0(const float* __restrict__ seq, const short* __restrict__ Wp,
                const float* __restrict__ bias, unsigned short* __restrict__ G) {
  const int btile = blockIdx.x % 40;
  const int rest  = blockIdx.x / 40;
  const int tg    = rest & 3;
  const int chunk = rest >> 2;
  const int tid = threadIdx.x, lane = tid & 63, wave = tid >> 6;
  const int nl = lane & 15, mq = lane >> 4;

  for (int mg = 0; mg < 4; ++mg) {
    const int t0 = chunk * 16 + mg * 4;
    f32x4 acc[4][4];
#pragma unroll
    for (int q = 0; q < 4; ++q) {
      int tile = tg * 16 + wave + 4 * q;
      float bv = bias[tile * 16 + nl];
#pragma unroll
      for (int mm = 0; mm < 4; ++mm) acc[mm][q] = (f32x4){bv, bv, bv, bv};
    }
    for (int kt = 0; kt < 2; ++kt) {
      short8 a[4];
      const int m = btile * 16 + nl;
      const int k0 = kt * 32 + mq * 8;
#pragma unroll
      for (int mm = 0; mm < 4; ++mm) {
#pragma unroll
        for (int j = 0; j < 8; ++j) {
          int k = k0 + j;
          float f = (k < IN_F) ? seq[((size_t)m * T_SEQ + (t0 + mm)) * IN_F + k] : 0.f;
          a[mm][j] = (short)f2bf(f);
        }
      }
#pragma unroll
      for (int q = 0; q < 4; ++q) {
        int tile = tg * 16 + wave + 4 * q;
        short8 b = *(const short8*)&Wp[(((size_t)tile * 2 + kt) * 64 + lane) * 8];
#pragma unroll
        for (int mm = 0; mm < 4; ++mm)
          acc[mm][q] = __builtin_amdgcn_mfma_f32_16x16x32_bf16(a[mm], b, acc[mm][q], 0, 0, 0);
      }
    }
#pragma unroll
    for (int mm = 0; mm < 4; ++mm)
#pragma unroll
      for (int q = 0; q < 4; ++q) {
        int tile = tg * 16 + wave + 4 * q;
        us4 o;
#pragma unroll
        for (int r = 0; r < 4; ++r) o[r] = f2bf(acc[mm][q][r]);
        *(us4*)&G[(((size_t)(t0 + mm) * 40 + btile) * 64 + tile) * 256 + lane * 4] = o;
      }
  }
}

// ---------------------------------------------------------------------------
// Fused 3-layer pipelined LSTM. 200 blocks = 10 supertiles (64 samples)
// x 5 stages {R0,G1,R1,G2,R2} x 4 blocks. Flags: f[l][S][hb] (rec),
// gf[l-1][S][gq] (gate feeders). Parity double-buffered LLC slabs; lag-2
// back-pressure prevents overwrite races. All comms = 64-bit relaxed
// agent-scope atomics (sc1 -> LLC, no cache-wide fences) - R7-proven.
// ---------------------------------------------------------------------------
__device__ __forceinline__ void rec_body(
    int l, int S, int hb,
    const short* __restrict__ Whhp, const unsigned short* __restrict__ G0,
    const unsigned long long* __restrict__ gxch_ro, unsigned long long* __restrict__ hxch,
    int* __restrict__ flags, int* __restrict__ gflags,
    const int* __restrict__ lens, float* __restrict__ c_state,
    unsigned short* h_sh, float* c_sh, int* len_sh)
{
  const int tid = threadIdx.x, lane = tid & 63, wave = tid >> 6;
  const int mq = lane >> 4, nl = lane & 15;
  const int lc = wave * 16 + nl;          // local col 0..63
  const int colown = hb * 64 + lc;

  short8 wreg[4][8];
#pragma unroll
  for (int g = 0; g < 4; ++g) {
    const int tile = g * 16 + hb * 4 + wave;
#pragma unroll
    for (int kt = 0; kt < 8; ++kt)
      wreg[g][kt] = *(const short8*)&Whhp[(((size_t)tile * 8 + kt) * 64 + lane) * 8];
  }
  for (int i = tid; i < 64 * 264; i += 256) h_sh[i] = 0;
  for (int i = tid; i < 64 * 65; i += 256) c_sh[i] = 0.f;
  if (tid < 64) len_sh[tid] = lens[S * 64 + tid];
  __syncthreads();

  const int fself = l * 40 + S * 4 + hb;

  for (int t = 0; t < T_SEQ; ++t) {
    const int par = t & 1;
    // ---- phase A: forward G wait (l>0) + feeder back-pressure (l<2) ----
    if (l > 0 && tid == 0)
      while (flg_ld(&gflags[(l - 1) * 40 + S * 4 + hb]) < t + 1) {}
    if (l < 2 && tid >= 4 && tid < 8)
      while (flg_ld(&gflags[l * 40 + S * 4 + (tid - 4)]) < t - 1) {}
    __syncthreads();

    // ---- G acquire -> acc init ----
    f32x4 acc[4][4];
    if (l == 0) {
#pragma unroll
      for (int m = 0; m < 4; ++m)
#pragma unroll
        for (int g = 0; g < 4; ++g) {
          const int tile = g * 16 + hb * 4 + wave;
          us4 gv = *(const us4*)&G0[(((size_t)t * 40 + S * 4 + m) * 64 + tile) * 256 + lane * 4];
#pragma unroll
          for (int r = 0; r < 4; ++r) acc[m][g][r] = b2f(gv[r]);
        }
    } else {
      const unsigned long long* gb =
          gxch_ro + ((size_t)((par * 2 + (l - 1)) * 10 + S) * 4 + hb) * 4096;
#pragma unroll
      for (int g = 0; g < 4; ++g)
#pragma unroll
        for (int m = 0; m < 4; ++m) {
          unsigned long long v = ato_ld(&gb[((g * 4 + wave) * 4 + m) * 64 + lane]);
          us4 gv; *(unsigned long long*)&gv = v;
#pragma unroll
          for (int r = 0; r < 4; ++r) acc[m][g][r] = b2f(gv[r]);
        }
    }
    // ---- recurrent MFMA over h[t-1] ----
#pragma unroll
    for (int kt = 0; kt < 8; ++kt) {
      short8 a[4];
#pragma unroll
      for (int m = 0; m < 4; ++m)
        a[m] = *(const short8*)&h_sh[(m * 16 + nl) * 264 + kt * 32 + mq * 8];
#pragma unroll
      for (int m = 0; m < 4; ++m)
#pragma unroll
        for (int g = 0; g < 4; ++g)
          acc[m][g] = __builtin_amdgcn_mfma_f32_16x16x32_bf16(a[m], wreg[g][kt], acc[m][g], 0, 0, 0);
    }
    // ---- gates (C/D: row=mq*4+r, col=nl), c in LDS ----
    unsigned short hv[16];
#pragma unroll
    for (int m = 0; m < 4; ++m)
#pragma unroll
      for (int r = 0; r < 4; ++r) {
        const int row = m * 16 + mq * 4 + r;
        float c_old = c_sh[row * 65 + lc];
        float cn = sigm(acc[m][1][r]) * c_old + sigm(acc[m][0][r]) * tanh_fast(acc[m][2][r]);
        float hn = sigm(acc[m][3][r]) * tanh_fast(cn);
        bool upd = t < len_sh[row];
        if (upd) c_sh[row * 65 + lc] = cn;
        hv[m * 4 + r] = upd ? f2bf(hn) : h_sh[row * 264 + colown];
      }
    __syncthreads();                       // (1) all h_sh reads done
#pragma unroll
    for (int m = 0; m < 4; ++m)
#pragma unroll
      for (int r = 0; r < 4; ++r)
        h_sh[(m * 16 + mq * 4 + r) * 264 + colown] = hv[m * 4 + r];
    __syncthreads();                       // (2) own cols in LDS
    // ---- publish own slab (8 KB) ----
    unsigned long long* myslab = hxch + ((size_t)((par * 3 + l) * 10 + S) * 4 + hb) * 1024;
    for (int j = tid; j < 1024; j += 256) {
      int sample = j >> 4, l4 = j & 15;
      unsigned long long v = *(const unsigned long long*)&h_sh[sample * 264 + hb * 64 + l4 * 4];
      ato_st(&myslab[j], v);
    }
    __syncthreads();                       // (3) vmcnt drained
    if (tid == 0) flg_st(&flags[fself], t + 1);
    // ---- peers ----
    if (tid < 3) {
      int p = tid + (tid >= hb ? 1 : 0);
      while (flg_ld(&flags[l * 40 + S * 4 + p]) < t + 1) {}
    }
    __syncthreads();                       // (4)
    for (int j = tid; j < 3072; j += 256) {
      int pp = j >> 10, jj = j & 1023;
      int p = pp + (pp >= hb ? 1 : 0);
      unsigned long long v =
          ato_ld(&hxch[((size_t)((par * 3 + l) * 10 + S) * 4 + p) * 1024 + jj]);
      int sample = jj >> 4, l4 = jj & 15;
      *(unsigned long long*)&h_sh[sample * 264 + p * 64 + l4 * 4] = v;
    }
    __syncthreads();                       // (5) h[t] complete
  }
  if (l == 2) {
#pragma unroll
    for (int m = 0; m < 4; ++m)
#pragma unroll
      for (int r = 0; r < 4; ++r) {
        const int row = m * 16 + mq * 4 + r;
        c_state[((size_t)S * 64 + row) * 256 + colown] = c_sh[row * 65 + lc];
      }
  }
}

__device__ __forceinline__ void gate_body(
    int l, int S, int gq,
    const short* __restrict__ Wihp, const float* __restrict__ biasl,
    unsigned long long* __restrict__ gxch, const unsigned long long* __restrict__ hxch_ro,
    int* __restrict__ flags, int* __restrict__ gflags,
    unsigned short* h_sh, float* c_sh)
{
  const int tid = threadIdx.x, lane = tid & 63, wave = tid >> 6;
  const int mq = lane >> 4, nl = lane & 15;

  short8 wreg[4][8];
#pragma unroll
  for (int g = 0; g < 4; ++g) {
    const int tile = g * 16 + gq * 4 + wave;
#pragma unroll
    for (int kt = 0; kt < 8; ++kt)
      wreg[g][kt] = *(const short8*)&Wihp[(((size_t)tile * 8 + kt) * 64 + lane) * 8];
  }
  for (int i = tid; i < 1024; i += 256) c_sh[i] = biasl[i];   // bias staged in c_sh
  __syncthreads();

  const int gfself = (l - 1) * 40 + S * 4 + gq;

  for (int t = 0; t < T_SEQ; ++t) {
    const int par = t & 1;
    if (tid < 4)
      while (flg_ld(&flags[(l - 1) * 40 + S * 4 + tid]) < t + 1) {}
    if (tid == 4)
      while (flg_ld(&flags[l * 40 + S * 4 + gq]) < t - 1) {}   // R_l consumed G[t-2]
    __syncthreads();                       // (A)
    // pull 4 h slabs of layer l-1 (32 KB) -> x in h_sh
    for (int j = tid; j < 4096; j += 256) {
      int pp = j >> 10, jj = j & 1023;
      unsigned long long v =
          ato_ld(&hxch_ro[((size_t)((par * 3 + (l - 1)) * 10 + S) * 4 + pp) * 1024 + jj]);
      int sample = jj >> 4, l4 = jj & 15;
      *(unsigned long long*)&h_sh[sample * 264 + pp * 64 + l4 * 4] = v;
    }
    __syncthreads();                       // (B)
    f32x4 acc[4][4];
#pragma unroll
    for (int g = 0; g < 4; ++g) {
      const int tile = g * 16 + gq * 4 + wave;
      float bv = c_sh[tile * 16 + nl];
#pragma unroll
      for (int m = 0; m < 4; ++m) acc[m][g] = (f32x4){bv, bv, bv, bv};
    }
#pragma unroll
    for (int kt = 0; kt < 8; ++kt) {
      short8 a[4];
#pragma unroll
      for (int m = 0; m < 4; ++m)
        a[m] = *(const short8*)&h_sh[(m * 16 + nl) * 264 + kt * 32 + mq * 8];
#pragma unroll
      for (int m = 0; m < 4; ++m)
#pragma unroll
        for (int g = 0; g < 4; ++g)
          acc[m][g] = __builtin_amdgcn_mfma_f32_16x16x32_bf16(a[m], wreg[g][kt], acc[m][g], 0, 0, 0);
    }
    unsigned long long* gb = gxch + ((size_t)((par * 2 + (l - 1)) * 10 + S) * 4 + gq) * 4096;
#pragma unroll
    for (int g = 0; g < 4; ++g)
#pragma unroll
      for (int m = 0; m < 4; ++m) {
        us4 o;
#pragma unroll
        for (int r = 0; r < 4; ++r) o[r] = f2bf(acc[m][g][r]);
        ato_st(&gb[((g * 4 + wave) * 4 + m) * 64 + lane], *(unsigned long long*)&o);
      }
    __syncthreads();                       // (C) drained
    if (tid == 0) flg_st(&gflags[gfself], t + 1);
  }
}

__global__ __launch_bounds__(256, 1)
void fused_lstm(const short* __restrict__ Whhp_all, const short* __restrict__ Wih1p,
                const short* __restrict__ Wih2p, const float* __restrict__ biasc,
                const unsigned short* __restrict__ G0, const int* __restrict__ lens,
                unsigned long long* __restrict__ hxch, unsigned long long* __restrict__ gxch,
                int* __restrict__ flags, int* __restrict__ gflags,
                float* __restrict__ c_state)
{
  __shared__ unsigned short h_sh[64 * 264];   // 33792 B (16B-aligned rows)
  __shared__ float c_sh[64 * 65];             // 16640 B (c state / bias stage)
  __shared__ int len_sh[64];
  const int bid = blockIdx.x;                 // 0..199
  const int S = bid % 10;
  const int role = bid / 10;                  // 0..19
  const int stage = role >> 2;                // 0:R0 1:G1 2:R1 3:G2 4:R2
  const int sub = role & 3;

  if (stage == 0)
    rec_body(0, S, sub, Whhp_all,            G0, gxch, hxch, flags, gflags, lens, c_state, h_sh, c_sh, len_sh);
  else if (stage == 1)
    gate_body(1, S, sub, Wih1p, biasc + G4,  gxch, hxch, flags, gflags, h_sh, c_sh);
  else if (stage == 2)
    rec_body(1, S, sub, Whhp_all + 262144,   G0, gxch, hxch, flags, gflags, lens, c_state, h_sh, c_sh, len_sh);
  else if (stage == 3)
    gate_body(2, S, sub, Wih2p, biasc + 2 * G4, gxch, hxch, flags, gflags, h_sh, c_sh);
  else
    rec_body(2, S, sub, Whhp_all + 524288,   G0, gxch, hxch, flags, gflags, lens, c_state, h_sh, c_sh, len_sh);
}

// ---------------------------------------------------------------------------
// Epilogue (verified R1-R7). E aliases c_state.
// ---------------------------------------------------------------------------
__global__ void k_norm(const float* __restrict__ E, float* __restrict__ E1,
                       float* __restrict__ En) {
  int row  = blockIdx.x * 4 + (threadIdx.x >> 6);
  int lane = threadIdx.x & 63;
  const float* e = E + (size_t)row * H_DIM;
  float v[4]; float ss = 0.f;
#pragma unroll
  for (int j = 0; j < 4; ++j) { v[j] = e[lane + 64 * j]; ss += v[j] * v[j]; }
#pragma unroll
  for (int m = 32; m >= 1; m >>= 1) ss += __shfl_xor(ss, m, 64);
  float nrm  = sqrtf(ss);
  float inv1 = 1.f / fmaxf(nrm, 1e-12f);
  float inv2 = 1.f / fmaxf(nrm * inv1, 1e-8f);
#pragma unroll
  for (int j = 0; j < 4; ++j) {
    float e1 = v[j] * inv1;
    E1[(size_t)row * H_DIM + lane + 64 * j] = e1;
    En[(size_t)row * H_DIM + lane + 64 * j] = e1 * inv2;
  }
}

__global__ void k_cent(const float* __restrict__ E1, float* __restrict__ C,
                       float* __restrict__ CnT) {
  int n = blockIdx.x;
  int lane = threadIdx.x;  // 64
  float v[4]; float ss = 0.f;
#pragma unroll
  for (int j = 0; j < 4; ++j) {
    int col = lane + 64 * j;
    float s = 0.f;
    for (int m = 0; m < M_UTT; ++m) s += E1[((size_t)n * M_UTT + m) * H_DIM + col];
    v[j] = s / (float)M_UTT;
    ss += v[j] * v[j];
  }
#pragma unroll
  for (int m = 32; m >= 1; m >>= 1) ss += __shfl_xor(ss, m, 64);
  float inv = 1.f / fmaxf(sqrtf(ss), 1e-8f);
#pragma unroll
  for (int j = 0; j < 4; ++j) {
    int col = lane + 64 * j;
    C[(size_t)n * H_DIM + col]  = v[j];
    CnT[(size_t)col * N_SPK + n] = v[j] * inv;
  }
}

__global__ void k_cm(const float* __restrict__ E1, const float* __restrict__ C,
                     float* __restrict__ Cmn) {
  int b    = blockIdx.x * 4 + (threadIdx.x >> 6);
  int lane = threadIdx.x & 63;
  int spk  = b / M_UTT;
  float v[4]; float ss = 0.f;
#pragma unroll
  for (int j = 0; j < 4; ++j) {
    int col = lane + 64 * j;
    v[j] = ((float)M_UTT * C[(size_t)spk * H_DIM + col] + E1[(size_t)b * H_DIM + col])
           / (float)(M_UTT - 1);
    ss += v[j] * v[j];
  }
#pragma unroll
  for (int m = 32; m >= 1; m >>= 1) ss += __shfl_xor(ss, m, 64);
  float inv = 1.f / fmaxf(sqrtf(ss), 1e-8f);
#pragma unroll
  for (int j = 0; j < 4; ++j)
    Cmn[(size_t)b * H_DIM + lane + 64 * j] = v[j] * inv;
}

__global__ void k_sim(const float* __restrict__ En, const float* __restrict__ CnT,
                      const float* __restrict__ Cmn, const float* __restrict__ w_sim,
                      const float* __restrict__ b_sim, float* __restrict__ S) {
  int b = blockIdx.x;
  int n = threadIdx.x;  // 64
  int diag = b / M_UTT;
  float w = w_sim[0], bb = b_sim[0];
  float s = 0.f;
  for (int k = 0; k < H_DIM; ++k) {
    float en = En[(size_t)b * H_DIM + k];
    float c  = (n == diag) ? Cmn[(size_t)b * H_DIM + k] : CnT[(size_t)k * N_SPK + n];
    s += en * c;
  }
  S[(size_t)b * N_SPK + n] = s * w + bb;
}

// ---------------------------------------------------------------------------
// Workspace layout (bytes). Total 222.4 MB (< proven-available ~266 MB).
// ---------------------------------------------------------------------------
#define O_WHH   0ull            // 3 x 524288 = 1572864
#define O_WIH0  1572864ull      // 131072
#define O_WIH1  1703936ull      // 524288
#define O_WIH2  2228224ull      // 524288
#define O_BIAS  2752512ull      // 12288
#define O_CST   2764800ull      // 655360 (fp32 c of layer2 = E)
#define O_E1    3420160ull      // 655360
#define O_EN    4075520ull      // 655360
#define O_C     4730880ull      // 65536
#define O_CNT   4796416ull      // 65536
#define O_CMN   4861952ull      // 655360
#define O_FLG   5517312ull      // 4096 (flags 120 ints @ +0; gflags 80 ints @ +512B)
#define O_HXCH  5521408ull      // 1966080 (2par x 3l x 10S x 4hb x 8KB)
#define O_GXCH  7487488ull      // 5242880 (2par x 2l x 10S x 4gq x 32KB)
#define O_G0    12730368ull     // 209715200

extern "C" void kernel_launch(void* const* d_in, const int* in_sizes, int n_in,
                              void* d_out, int out_size, void* d_ws, size_t ws_size,
                              hipStream_t stream) {
  const float* seq   = (const float*)d_in[0];
  const int*   lens  = (const int*)d_in[1];
  const float* w_sim = (const float*)d_in[2];
  const float* b_sim = (const float*)d_in[3];
  const float* Wih[3] = {(const float*)d_in[4],  (const float*)d_in[8],  (const float*)d_in[12]};
  const float* Whh[3] = {(const float*)d_in[5],  (const float*)d_in[9],  (const float*)d_in[13]};
  const float* bih[3] = {(const float*)d_in[6],  (const float*)d_in[10], (const float*)d_in[14]};
  const float* bhh[3] = {(const float*)d_in[7],  (const float*)d_in[11], (const float*)d_in[15]};

  char* ws = (char*)d_ws;
  short* Whhp_all = (short*)(ws + O_WHH);
  short* Wihp[3] = {(short*)(ws + O_WIH0), (short*)(ws + O_WIH1), (short*)(ws + O_WIH2)};
  float* biasc = (float*)(ws + O_BIAS);
  float* c_state = (float*)(ws + O_CST);
  float* E1  = (float*)(ws + O_E1);
  float* En  = (float*)(ws + O_EN);
  float* C   = (float*)(ws + O_C);
  float* CnT = (float*)(ws + O_CNT);
  float* Cmn = (float*)(ws + O_CMN);
  int* flags  = (int*)(ws + O_FLG);
  int* gflags = (int*)(ws + O_FLG + 512);
  unsigned long long* hxch = (unsigned long long*)(ws + O_HXCH);
  unsigned long long* gxch = (unsigned long long*)(ws + O_GXCH);
  unsigned short* G0 = (unsigned short*)(ws + O_G0);
  float* S = (float*)d_out;

  // ---- packs ----
  pack_w_kernel<<<32, 256, 0, stream>>>(Wih[0], Wihp[0], IN_F, 2);
  pack_w_kernel<<<128, 256, 0, stream>>>(Whh[0], Whhp_all, H_DIM, 8);
  pack_w_kernel<<<128, 256, 0, stream>>>(Whh[1], Whhp_all + 262144, H_DIM, 8);
  pack_w_kernel<<<128, 256, 0, stream>>>(Whh[2], Whhp_all + 524288, H_DIM, 8);
  pack_w_kernel<<<128, 256, 0, stream>>>(Wih[1], Wihp[1], H_DIM, 8);
  pack_w_kernel<<<128, 256, 0, stream>>>(Wih[2], Wihp[2], H_DIM, 8);
  for (int l = 0; l < 3; ++l)
    bias_sum_kernel<<<4, 256, 0, stream>>>(bih[l], bhh[l], biasc + l * G4);

  // ---- layer-0 gate GEMM (full T) ----
  gate_gemm0<<<1600, 256, 0, stream>>>(seq, Wihp[0], biasc, G0);

  // ---- fused 3-layer pipeline ----
  hipMemsetAsync(ws + O_FLG, 0, 4096, stream);
  fused_lstm<<<200, 256, 0, stream>>>(Whhp_all, Wihp[1], Wihp[2], biasc, G0, lens,
                                      hxch, gxch, flags, gflags, c_state);

  // ---- similarity epilogue (E = c_state) ----
  k_norm<<<160, 256, 0, stream>>>(c_state, E1, En);
  k_cent<<<N_SPK, 64, 0, stream>>>(E1, C, CnT);
  k_cm<<<160, 256, 0, stream>>>(E1, C, Cmn);
  k_sim<<<B_TOT, 64, 0, stream>>>(En, CnT, Cmn, w_sim, b_sim, S);
}